// Round 5
// baseline (336.933 us; speedup 1.0000x reference)
//
#include <hip/hip_runtime.h>
#include <hip/hip_bf16.h>

// PointPillarsScatter: out[b][c][y][x] = vf[p][c] where coords[p]=(b,0,y,x),
// last p wins on duplicates (numpy scatter semantics); 0 elsewhere.
// B=4, C=64, NY=512, NX=512 fixed by the problem.

#define NXC 512
#define NYC 512
#define BC 4
#define CC 64
#define SLOTS_PER_BATCH (NXC * NYC)        // 262144 = 2^18
#define TOTAL_SLOTS (BC * SLOTS_PER_BATCH) // 1048576

typedef float vf4 __attribute__((ext_vector_type(4)));  // native vec for nt ops

// Phase 2: deterministic "last pillar wins" via atomicMax on pillar index.
__global__ void build_winner_kernel(const int* __restrict__ coords,
                                    int* __restrict__ winner, int P) {
    int p = blockIdx.x * blockDim.x + threadIdx.x;
    if (p >= P) return;
    int4 c = ((const int4*)coords)[p];      // (b, z, y, x)
    int flat = c.x * SLOTS_PER_BATCH + c.z * NXC + c.w;
    atomicMax(&winner[flat], p);
}

// Phase 3: inverse-map gather. Each thread owns 4 consecutive x-slots and a
// 16-channel QUARTER (blockIdx&3) => grid 4096 blocks. Live gather data is
// only 16 vf4/thread, so the compiler can hoist all gathers ahead of the
// store stream (no latency stall mid-stream).
// Stores: 16B/lane, wave-contiguous 1KiB per instr, NT (write-once).
// Gathers: exactly one 64B line per occupied pillar-quarter, NT (read-once).
__global__ __launch_bounds__(256) void scatter_out_kernel(
        const float* __restrict__ vf,
        const int* __restrict__ winner,
        float* __restrict__ out) {
    int blk = blockIdx.x;
    int q   = blk & 3;                               // channel quarter: 0..3
    int tq  = ((blk >> 2) << 8) + threadIdx.x;       // slot-quad id, 0..262143
    int b   = tq >> 16;                              // batch
    int rem = (tq << 2) & (SLOTS_PER_BATCH - 1);     // y*NX + x

    int4 w = ((const int4*)winner)[tq];              // coalesced 16B winner read

    float* obase = out + (size_t)b * (CC * SLOTS_PER_BATCH)
                       + (size_t)(q << 4) * SLOTS_PER_BATCH + rem;
    const int coff = q << 2;                         // quarter offset in vf4s
    const vf4* v0 = (const vf4*)(vf + (size_t)w.x * CC) + coff;
    const vf4* v1 = (const vf4*)(vf + (size_t)w.y * CC) + coff;
    const vf4* v2 = (const vf4*)(vf + (size_t)w.z * CC) + coff;
    const vf4* v3 = (const vf4*)(vf + (size_t)w.w * CC) + coff;

    const vf4 z4 = (vf4)(0.f);
    vf4 a[4], bb[4], cc[4], dd[4];
    #pragma unroll
    for (int j = 0; j < 4; ++j) {                    // hoisted gather block
        a[j] = bb[j] = cc[j] = dd[j] = z4;
        if (w.x >= 0) a[j]  = __builtin_nontemporal_load(v0 + j);
        if (w.y >= 0) bb[j] = __builtin_nontemporal_load(v1 + j);
        if (w.z >= 0) cc[j] = __builtin_nontemporal_load(v2 + j);
        if (w.w >= 0) dd[j] = __builtin_nontemporal_load(v3 + j);
    }

    #pragma unroll
    for (int j = 0; j < 4; ++j) {                    // pure store stream
        // 4x4 transpose: rows = 4 channels, cols = 4 consecutive x
        vf4* s0 = (vf4*)(obase + (size_t)(4 * j + 0) * SLOTS_PER_BATCH);
        vf4* s1 = (vf4*)(obase + (size_t)(4 * j + 1) * SLOTS_PER_BATCH);
        vf4* s2 = (vf4*)(obase + (size_t)(4 * j + 2) * SLOTS_PER_BATCH);
        vf4* s3 = (vf4*)(obase + (size_t)(4 * j + 3) * SLOTS_PER_BATCH);
        vf4 r0 = {a[j].x, bb[j].x, cc[j].x, dd[j].x};
        vf4 r1 = {a[j].y, bb[j].y, cc[j].y, dd[j].y};
        vf4 r2 = {a[j].z, bb[j].z, cc[j].z, dd[j].z};
        vf4 r3 = {a[j].w, bb[j].w, cc[j].w, dd[j].w};
        __builtin_nontemporal_store(r0, s0);
        __builtin_nontemporal_store(r1, s1);
        __builtin_nontemporal_store(r2, s2);
        __builtin_nontemporal_store(r3, s3);
    }
}

extern "C" void kernel_launch(void* const* d_in, const int* in_sizes, int n_in,
                              void* d_out, int out_size, void* d_ws, size_t ws_size,
                              hipStream_t stream) {
    const float* vf    = (const float*)d_in[0];   // [P, 64] float32
    const int* coords  = (const int*)d_in[1];     // [P, 4] int32 (b,z,y,x)
    int P = in_sizes[0] / CC;

    int* winner = (int*)d_ws;                     // [TOTAL_SLOTS] int32 (4 MiB)
    float* out  = (float*)d_out;                  // [4,64,512,512] float32

    // Phase 1: winner = -1 everywhere (0xFF bytes == -1 as int32).
    (void)hipMemsetAsync(winner, 0xFF, (size_t)TOTAL_SLOTS * sizeof(int), stream);

    // Phase 2: last-write-wins winner table.
    build_winner_kernel<<<(P + 255) / 256, 256, 0, stream>>>(coords, winner, P);

    // Phase 3: dense coalesced output generation (writes every element).
    // 4096 blocks: groups of 4 cover channel quarters of 256 slot-quads.
    scatter_out_kernel<<<(TOTAL_SLOTS / 4 / 256) * 4, 256, 0, stream>>>(vf, winner, out);
}

// Round 6
// 316.564 us; speedup vs baseline: 1.0643x; 1.0643x over previous
//
#include <hip/hip_runtime.h>
#include <hip/hip_bf16.h>

// PointPillarsScatter: out[b][c][y][x] = vf[p][c] where coords[p]=(b,0,y,x),
// last p wins on duplicates (numpy scatter semantics); 0 elsewhere.
// B=4, C=64, NY=512, NX=512 fixed by the problem.

#define NXC 512
#define NYC 512
#define BC 4
#define CC 64
#define SLOTS_PER_BATCH (NXC * NYC)        // 262144 = 2^18
#define TOTAL_SLOTS (BC * SLOTS_PER_BATCH) // 1048576

typedef float vf4 __attribute__((ext_vector_type(4)));

// Phase 2: deterministic "last pillar wins" via atomicMax on pillar index.
__global__ void build_winner_kernel(const int* __restrict__ coords,
                                    int* __restrict__ winner, int P) {
    int p = blockIdx.x * blockDim.x + threadIdx.x;
    if (p >= P) return;
    int4 c = ((const int4*)coords)[p];      // (b, z, y, x)
    int flat = c.x * SLOTS_PER_BATCH + c.z * NXC + c.w;
    atomicMax(&winner[flat], p);
}

// Phase 3: inverse-map gather. Each thread owns 4 consecutive x-slots and a
// 32-channel HALF (blockIdx parity) => grid 2048 blocks.
// Stores: 16B/lane, wave-contiguous 1KiB per instr, PLAIN (L2 write-back
// merges full lines — A/B test vs NT which bypasses L2).
// Gathers: one 128B line per occupied pillar-half per thread; sequential 16B
// loads of that line hit L2 after the first miss.
__global__ __launch_bounds__(256) void scatter_out_kernel(
        const float* __restrict__ vf,
        const int* __restrict__ winner,
        float* __restrict__ out) {
    int blk = blockIdx.x;
    int h   = blk & 1;                               // channel half: 0 or 1
    int tq  = ((blk >> 1) << 8) + threadIdx.x;       // slot-quad id, 0..262143
    int b   = tq >> 16;                              // batch
    int rem = (tq << 2) & (SLOTS_PER_BATCH - 1);     // y*NX + x

    int4 w = ((const int4*)winner)[tq];              // coalesced 16B winner read

    float* obase = out + (size_t)b * (CC * SLOTS_PER_BATCH)
                       + (size_t)(h << 5) * SLOTS_PER_BATCH + rem;
    const int coff = h << 3;                         // half offset in float4s
    const vf4* v0 = (const vf4*)(vf + (size_t)w.x * CC) + coff;
    const vf4* v1 = (const vf4*)(vf + (size_t)w.y * CC) + coff;
    const vf4* v2 = (const vf4*)(vf + (size_t)w.z * CC) + coff;
    const vf4* v3 = (const vf4*)(vf + (size_t)w.w * CC) + coff;

    const vf4 z4 = (vf4)(0.f);
    #pragma unroll
    for (int j = 0; j < 8; ++j) {                    // 8 channel-quads in half
        vf4 a = z4, bb = z4, cc = z4, dd = z4;
        if (w.x >= 0) a  = v0[j];
        if (w.y >= 0) bb = v1[j];
        if (w.z >= 0) cc = v2[j];
        if (w.w >= 0) dd = v3[j];

        // 4x4 transpose: rows = 4 channels, cols = 4 consecutive x
        vf4* s0 = (vf4*)(obase + (size_t)(4 * j + 0) * SLOTS_PER_BATCH);
        vf4* s1 = (vf4*)(obase + (size_t)(4 * j + 1) * SLOTS_PER_BATCH);
        vf4* s2 = (vf4*)(obase + (size_t)(4 * j + 2) * SLOTS_PER_BATCH);
        vf4* s3 = (vf4*)(obase + (size_t)(4 * j + 3) * SLOTS_PER_BATCH);
        vf4 r0 = {a.x, bb.x, cc.x, dd.x};
        vf4 r1 = {a.y, bb.y, cc.y, dd.y};
        vf4 r2 = {a.z, bb.z, cc.z, dd.z};
        vf4 r3 = {a.w, bb.w, cc.w, dd.w};
        *s0 = r0;
        *s1 = r1;
        *s2 = r2;
        *s3 = r3;
    }
}

extern "C" void kernel_launch(void* const* d_in, const int* in_sizes, int n_in,
                              void* d_out, int out_size, void* d_ws, size_t ws_size,
                              hipStream_t stream) {
    const float* vf    = (const float*)d_in[0];   // [P, 64] float32
    const int* coords  = (const int*)d_in[1];     // [P, 4] int32 (b,z,y,x)
    int P = in_sizes[0] / CC;

    int* winner = (int*)d_ws;                     // [TOTAL_SLOTS] int32 (4 MiB)
    float* out  = (float*)d_out;                  // [4,64,512,512] float32

    // Phase 1: winner = -1 everywhere (0xFF bytes == -1 as int32).
    (void)hipMemsetAsync(winner, 0xFF, (size_t)TOTAL_SLOTS * sizeof(int), stream);

    // Phase 2: last-write-wins winner table.
    build_winner_kernel<<<(P + 255) / 256, 256, 0, stream>>>(coords, winner, P);

    // Phase 3: dense coalesced output generation (writes every element).
    // 2048 blocks: even/odd pairs cover channel halves of 256 slot-quads.
    scatter_out_kernel<<<(TOTAL_SLOTS / 4 / 256) * 2, 256, 0, stream>>>(vf, winner, out);
}

// Round 7
// 306.732 us; speedup vs baseline: 1.0985x; 1.0321x over previous
//
#include <hip/hip_runtime.h>
#include <hip/hip_bf16.h>

// PointPillarsScatter: out[b][c][y][x] = vf[p][c] where coords[p]=(b,0,y,x),
// last p wins on duplicates (numpy scatter semantics); 0 elsewhere.
// B=4, C=64, NY=512, NX=512 fixed by the problem.

#define NXC 512
#define NYC 512
#define BC 4
#define CC 64
#define SLOTS_PER_BATCH (NXC * NYC)        // 262144 = 2^18
#define TOTAL_SLOTS (BC * SLOTS_PER_BATCH) // 1048576

typedef float vf4 __attribute__((ext_vector_type(4)));

// Phase 2: deterministic "last pillar wins" via atomicMax on pillar index.
__global__ void build_winner_kernel(const int* __restrict__ coords,
                                    int* __restrict__ winner, int P) {
    int p = blockIdx.x * blockDim.x + threadIdx.x;
    if (p >= P) return;
    int4 c = ((const int4*)coords)[p];      // (b, z, y, x)
    int flat = c.x * SLOTS_PER_BATCH + c.z * NXC + c.w;
    atomicMax(&winner[flat], p);
}

// Phase 3: inverse-map gather. Each thread owns 4 consecutive x-slots and a
// 32-channel HALF (blockIdx parity) => grid 2048 blocks (R4 structure: best).
// NT stores (bypass L2 — +17us vs plain, R6), plain gathers (NT loads
// regressed, R5). NEW: explicit distance-4 software pipeline so every store
// group's gathers have been in flight for 4 iterations (~16 loads) before use.
__global__ __launch_bounds__(256) void scatter_out_kernel(
        const float* __restrict__ vf,
        const int* __restrict__ winner,
        float* __restrict__ out) {
    int blk = blockIdx.x;
    int h   = blk & 1;                               // channel half: 0 or 1
    int tq  = ((blk >> 1) << 8) + threadIdx.x;       // slot-quad id, 0..262143
    int b   = tq >> 16;                              // batch
    int rem = (tq << 2) & (SLOTS_PER_BATCH - 1);     // y*NX + x

    int4 w = ((const int4*)winner)[tq];              // coalesced 16B winner read

    float* obase = out + (size_t)b * (CC * SLOTS_PER_BATCH)
                       + (size_t)(h << 5) * SLOTS_PER_BATCH + rem;
    const int coff = h << 3;                         // half offset in float4s
    const vf4* v0 = (const vf4*)(vf + (size_t)w.x * CC) + coff;
    const vf4* v1 = (const vf4*)(vf + (size_t)w.y * CC) + coff;
    const vf4* v2 = (const vf4*)(vf + (size_t)w.z * CC) + coff;
    const vf4* v3 = (const vf4*)(vf + (size_t)w.w * CC) + coff;

    const vf4 z4 = (vf4)(0.f);
    vf4 pa[4], pb[4], pc[4], pd[4];                  // 4-deep ring, 16 vf4 live

    // Prologue: issue gathers for j=0..3 (16 independent loads in flight).
    #pragma unroll
    for (int j = 0; j < 4; ++j) {
        pa[j] = pb[j] = pc[j] = pd[j] = z4;
        if (w.x >= 0) pa[j] = v0[j];
        if (w.y >= 0) pb[j] = v1[j];
        if (w.z >= 0) pc[j] = v2[j];
        if (w.w >= 0) pd[j] = v3[j];
    }

    // Steady state: store j (loads long in flight), issue gathers for j+4.
    #pragma unroll
    for (int j = 0; j < 8; ++j) {
        int s = j & 3;
        vf4 a = pa[s], bb = pb[s], cc = pc[s], dd = pd[s];

        if (j + 4 < 8) {
            pa[s] = pb[s] = pc[s] = pd[s] = z4;
            if (w.x >= 0) pa[s] = v0[j + 4];
            if (w.y >= 0) pb[s] = v1[j + 4];
            if (w.z >= 0) pc[s] = v2[j + 4];
            if (w.w >= 0) pd[s] = v3[j + 4];
        }

        // 4x4 transpose: rows = 4 channels, cols = 4 consecutive x
        vf4* s0 = (vf4*)(obase + (size_t)(4 * j + 0) * SLOTS_PER_BATCH);
        vf4* s1 = (vf4*)(obase + (size_t)(4 * j + 1) * SLOTS_PER_BATCH);
        vf4* s2 = (vf4*)(obase + (size_t)(4 * j + 2) * SLOTS_PER_BATCH);
        vf4* s3 = (vf4*)(obase + (size_t)(4 * j + 3) * SLOTS_PER_BATCH);
        vf4 r0 = {a.x, bb.x, cc.x, dd.x};
        vf4 r1 = {a.y, bb.y, cc.y, dd.y};
        vf4 r2 = {a.z, bb.z, cc.z, dd.z};
        vf4 r3 = {a.w, bb.w, cc.w, dd.w};
        __builtin_nontemporal_store(r0, s0);
        __builtin_nontemporal_store(r1, s1);
        __builtin_nontemporal_store(r2, s2);
        __builtin_nontemporal_store(r3, s3);
    }
}

extern "C" void kernel_launch(void* const* d_in, const int* in_sizes, int n_in,
                              void* d_out, int out_size, void* d_ws, size_t ws_size,
                              hipStream_t stream) {
    const float* vf    = (const float*)d_in[0];   // [P, 64] float32
    const int* coords  = (const int*)d_in[1];     // [P, 4] int32 (b,z,y,x)
    int P = in_sizes[0] / CC;

    int* winner = (int*)d_ws;                     // [TOTAL_SLOTS] int32 (4 MiB)
    float* out  = (float*)d_out;                  // [4,64,512,512] float32

    // Phase 1: winner = -1 everywhere (0xFF bytes == -1 as int32).
    (void)hipMemsetAsync(winner, 0xFF, (size_t)TOTAL_SLOTS * sizeof(int), stream);

    // Phase 2: last-write-wins winner table.
    build_winner_kernel<<<(P + 255) / 256, 256, 0, stream>>>(coords, winner, P);

    // Phase 3: dense coalesced output generation (writes every element).
    // 2048 blocks: even/odd pairs cover channel halves of 256 slot-quads.
    scatter_out_kernel<<<(TOTAL_SLOTS / 4 / 256) * 2, 256, 0, stream>>>(vf, winner, out);
}

// Round 8
// 298.770 us; speedup vs baseline: 1.1277x; 1.0266x over previous
//
#include <hip/hip_runtime.h>
#include <hip/hip_bf16.h>

// PointPillarsScatter: out[b][c][y][x] = vf[p][c] where coords[p]=(b,0,y,x),
// last p wins on duplicates (numpy scatter semantics); 0 elsewhere.
// B=4, C=64, NY=512, NX=512 fixed by the problem.
//
// Final structure (best of R0-R7 experiment matrix):
//   phase 1: memset winner=-1 (4 MiB)
//   phase 2: atomicMax(winner[flat], p)  -> deterministic last-write-wins
//   phase 3: dense inverse-map gather, 4 slots x 32-channel half per thread,
//            NT dwordx4 stores (bypass L2: +17us vs plain, R6 A/B),
//            plain 16B gathers (NT loads regressed, R5),
//            no explicit pipelining (compiler already hoists, R7 A/B).
// Measured ceiling: scatter ~75us = 307 MB @ ~4.3 TB/s effective; the gap to
// pure-stream 6.3 TB/s is the random-128B-gather + NT-write-stream mix cost
// (occupancy/hoist/pipeline attacks all neutral or negative).

#define NXC 512
#define NYC 512
#define BC 4
#define CC 64
#define SLOTS_PER_BATCH (NXC * NYC)        // 262144 = 2^18
#define TOTAL_SLOTS (BC * SLOTS_PER_BATCH) // 1048576

typedef float vf4 __attribute__((ext_vector_type(4)));

// Phase 2: deterministic "last pillar wins" via atomicMax on pillar index.
__global__ void build_winner_kernel(const int* __restrict__ coords,
                                    int* __restrict__ winner, int P) {
    int p = blockIdx.x * blockDim.x + threadIdx.x;
    if (p >= P) return;
    int4 c = ((const int4*)coords)[p];      // (b, z, y, x)
    int flat = c.x * SLOTS_PER_BATCH + c.z * NXC + c.w;
    atomicMax(&winner[flat], p);
}

// Phase 3: inverse-map gather. Each thread owns 4 consecutive x-slots and a
// 32-channel HALF (blockIdx parity) => grid 2048 blocks, 32 waves/CU.
// Stores: 16B/lane, wave-contiguous 1KiB per instr, NT (write-once).
// Gathers: one 128B line per occupied pillar-half per thread, exec-masked
// (empty lanes generate no traffic; ~11% slot occupancy).
__global__ __launch_bounds__(256) void scatter_out_kernel(
        const float* __restrict__ vf,
        const int* __restrict__ winner,
        float* __restrict__ out) {
    int blk = blockIdx.x;
    int h   = blk & 1;                               // channel half: 0 or 1
    int tq  = ((blk >> 1) << 8) + threadIdx.x;       // slot-quad id, 0..262143
    int b   = tq >> 16;                              // batch
    int rem = (tq << 2) & (SLOTS_PER_BATCH - 1);     // y*NX + x

    int4 w = ((const int4*)winner)[tq];              // coalesced 16B winner read

    float* obase = out + (size_t)b * (CC * SLOTS_PER_BATCH)
                       + (size_t)(h << 5) * SLOTS_PER_BATCH + rem;
    const int coff = h << 3;                         // half offset in float4s
    const vf4* v0 = (const vf4*)(vf + (size_t)w.x * CC) + coff;
    const vf4* v1 = (const vf4*)(vf + (size_t)w.y * CC) + coff;
    const vf4* v2 = (const vf4*)(vf + (size_t)w.z * CC) + coff;
    const vf4* v3 = (const vf4*)(vf + (size_t)w.w * CC) + coff;

    const vf4 z4 = (vf4)(0.f);
    #pragma unroll
    for (int j = 0; j < 8; ++j) {                    // 8 channel-quads in half
        vf4 a = z4, bb = z4, cc = z4, dd = z4;
        if (w.x >= 0) a  = v0[j];
        if (w.y >= 0) bb = v1[j];
        if (w.z >= 0) cc = v2[j];
        if (w.w >= 0) dd = v3[j];

        // 4x4 transpose: rows = 4 channels, cols = 4 consecutive x
        vf4* s0 = (vf4*)(obase + (size_t)(4 * j + 0) * SLOTS_PER_BATCH);
        vf4* s1 = (vf4*)(obase + (size_t)(4 * j + 1) * SLOTS_PER_BATCH);
        vf4* s2 = (vf4*)(obase + (size_t)(4 * j + 2) * SLOTS_PER_BATCH);
        vf4* s3 = (vf4*)(obase + (size_t)(4 * j + 3) * SLOTS_PER_BATCH);
        vf4 r0 = {a.x, bb.x, cc.x, dd.x};
        vf4 r1 = {a.y, bb.y, cc.y, dd.y};
        vf4 r2 = {a.z, bb.z, cc.z, dd.z};
        vf4 r3 = {a.w, bb.w, cc.w, dd.w};
        __builtin_nontemporal_store(r0, s0);
        __builtin_nontemporal_store(r1, s1);
        __builtin_nontemporal_store(r2, s2);
        __builtin_nontemporal_store(r3, s3);
    }
}

extern "C" void kernel_launch(void* const* d_in, const int* in_sizes, int n_in,
                              void* d_out, int out_size, void* d_ws, size_t ws_size,
                              hipStream_t stream) {
    const float* vf    = (const float*)d_in[0];   // [P, 64] float32
    const int* coords  = (const int*)d_in[1];     // [P, 4] int32 (b,z,y,x)
    int P = in_sizes[0] / CC;

    int* winner = (int*)d_ws;                     // [TOTAL_SLOTS] int32 (4 MiB)
    float* out  = (float*)d_out;                  // [4,64,512,512] float32

    // Phase 1: winner = -1 everywhere (0xFF bytes == -1 as int32).
    (void)hipMemsetAsync(winner, 0xFF, (size_t)TOTAL_SLOTS * sizeof(int), stream);

    // Phase 2: last-write-wins winner table.
    build_winner_kernel<<<(P + 255) / 256, 256, 0, stream>>>(coords, winner, P);

    // Phase 3: dense coalesced output generation (writes every element).
    // 2048 blocks: even/odd pairs cover channel halves of 256 slot-quads.
    scatter_out_kernel<<<(TOTAL_SLOTS / 4 / 256) * 2, 256, 0, stream>>>(vf, winner, out);
}